// Round 1
// baseline (44.855 us; speedup 1.0000x reference)
//
#include <hip/hip_runtime.h>

// mem_update_MSF: LIF-style membrane update with multi-synaptic fire.
// x: [T=8, B=32, C=128, H=32, W=32] f32.  out same shape, f32 spike counts.
// Recurrence per neuron i:
//   mask = spike>0; mem = mem*0.25*(1-mask) + x[t]; spike = sum_d (mem >= 0.5+d)
// Memory-bound streaming: 268 MB traffic, no reuse across neurons.

constexpr int T = 8;

__device__ __forceinline__ float msf_count(float m) {
    // Explicit threshold compares — exact match to the reference's Heaviside sum.
    float s = (m >= 0.5f) ? 1.0f : 0.0f;
    s += (m >= 1.5f) ? 1.0f : 0.0f;
    s += (m >= 2.5f) ? 1.0f : 0.0f;
    s += (m >= 3.5f) ? 1.0f : 0.0f;
    return s;
}

__global__ __launch_bounds__(256) void mem_update_msf_kernel(
        const float4* __restrict__ x, float4* __restrict__ out, int NV) {
    int i = blockIdx.x * blockDim.x + threadIdx.x;
    if (i >= NV) return;

    float m0 = 0.f, m1 = 0.f, m2 = 0.f, m3 = 0.f;
    float s0 = 0.f, s1 = 0.f, s2 = 0.f, s3 = 0.f;

#pragma unroll
    for (int t = 0; t < T; ++t) {
        float4 xt = x[(size_t)t * NV + i];

        // keep = (1 - mask) is exactly 0.0 or 1.0; mem*0.25 is an exact
        // exponent shift -> single rounding at the add, matches numpy bitwise.
        m0 = m0 * 0.25f * ((s0 > 0.f) ? 0.f : 1.f) + xt.x;
        m1 = m1 * 0.25f * ((s1 > 0.f) ? 0.f : 1.f) + xt.y;
        m2 = m2 * 0.25f * ((s2 > 0.f) ? 0.f : 1.f) + xt.z;
        m3 = m3 * 0.25f * ((s3 > 0.f) ? 0.f : 1.f) + xt.w;

        s0 = msf_count(m0);
        s1 = msf_count(m1);
        s2 = msf_count(m2);
        s3 = msf_count(m3);

        float4 o;
        o.x = s0; o.y = s1; o.z = s2; o.w = s3;
        out[(size_t)t * NV + i] = o;
    }
}

extern "C" void kernel_launch(void* const* d_in, const int* in_sizes, int n_in,
                              void* d_out, int out_size, void* d_ws, size_t ws_size,
                              hipStream_t stream) {
    const float* x = (const float*)d_in[0];
    float* out = (float*)d_out;

    const int total = out_size;          // T * B * C * H * W = 33,554,432
    const int N = total / T;             // neurons per timestep = 4,194,304
    const int NV = N / 4;                // float4 groups = 1,048,576

    const int block = 256;
    const int grid = (NV + block - 1) / block;  // 4096

    mem_update_msf_kernel<<<grid, block, 0, stream>>>(
        (const float4*)x, (float4*)out, NV);
}